// Round 21
// baseline (480.908 us; speedup 1.0000x reference)
//
#include <hip/hip_runtime.h>
#include <hip/hip_bf16.h>
#include <stdint.h>

typedef unsigned short u16;
typedef __bf16 bf16x8 __attribute__((ext_vector_type(8)));
typedef unsigned short u16x8 __attribute__((ext_vector_type(8)));
typedef float f32x4 __attribute__((ext_vector_type(4)));

__device__ __forceinline__ float bf2f(u16 u){ union{float f; unsigned i;} v; v.i = ((unsigned)u)<<16; return v.f; }
__device__ __forceinline__ u16 f2bf(float f){ union{float f; unsigned i;} v; v.f=f; unsigned r = v.i + 0x7FFFu + ((v.i>>16)&1u); return (u16)(r>>16); }
// native-cast path: compiler emits HW bf16 cvt (RNE, same rounding) -- far fewer VALU ops
__device__ __forceinline__ u16 f2bfn(float f){ __bf16 b = (__bf16)f; union{__bf16 b; u16 u;} v; v.b = b; return v.u; }

__device__ __forceinline__ void async16(const void* g, void* l){
  __builtin_amdgcn_global_load_lds((const __attribute__((address_space(1))) void*)g,
                                   (__attribute__((address_space(3))) void*)l, 16, 0, 0);
}

// ---------------- f32 -> bf16 elementwise cast ----------------
__global__ __launch_bounds__(256) void cvt_f2b(const float* __restrict__ src, u16* __restrict__ dst, int n)
{
  int i = (blockIdx.x * 256 + threadIdx.x) * 4;
  if (i < n) {
    float4 v = *(const float4*)&src[i];
    ushort4 o;
    o.x = f2bf(v.x); o.y = f2bf(v.y); o.z = f2bf(v.z); o.w = f2bf(v.w);
    *(ushort4*)&dst[i] = o;
  }
}

// ---------------- f32 src -> bf16 transposed dst, 64x64 tiles ----------------
__global__ __launch_bounds__(256) void transpose2d_f2b(const float* __restrict__ src, u16* __restrict__ dst,
                                                       int src_rows, int src_cols)
{
  __shared__ u16 tile[64][72];
  const int r0 = blockIdx.y << 6, c0 = blockIdx.x << 6;
  const int t = threadIdx.x;
  #pragma unroll
  for (int i=0;i<4;i++){
    int slot = t + (i<<8);
    int r = slot >> 4, cv = (slot & 15) << 2;
    float4 v = *(const float4*)&src[(size_t)(r0+r)*src_cols + c0 + cv];
    tile[r][cv+0] = f2bf(v.x); tile[r][cv+1] = f2bf(v.y);
    tile[r][cv+2] = f2bf(v.z); tile[r][cv+3] = f2bf(v.w);
  }
  __syncthreads();
  #pragma unroll
  for (int i=0;i<2;i++){
    int slot = t + (i<<8);
    int cr = slot >> 3, rv = (slot & 7) << 3;
    u16x8 v;
    #pragma unroll
    for (int e=0;e<8;e++) v[e] = tile[rv+e][cr];
    *(u16x8*)&dst[(size_t)(c0+cr)*src_rows + r0 + rv] = v;
  }
}

// ---------------- V transpose ----------------
__global__ __launch_bounds__(256) void transpose_v(const u16* __restrict__ qkv, u16* __restrict__ vt)
{
  __shared__ u16 tile[64][72];
  const int bh = blockIdx.z;
  const int b = bh >> 4, h = bh & 15;
  const u16* src = qkv + (size_t)b*2048*6144 + 4096 + h*128;
  u16* dst = vt + (size_t)bh*128*2048;
  const int t0 = blockIdx.y << 6, d0 = blockIdx.x << 6;
  const int t = threadIdx.x;
  #pragma unroll
  for (int i=0;i<2;i++){
    int slot = t + (i<<8);
    int r = slot >> 3, cv = (slot & 7) << 3;
    *(u16x8*)&tile[r][cv] = *(const u16x8*)&src[(size_t)(t0+r)*6144 + d0 + cv];
  }
  __syncthreads();
  #pragma unroll
  for (int i=0;i<2;i++){
    int slot = t + (i<<8);
    int cr = slot >> 3, rv = (slot & 7) << 3;
    u16x8 v;
    #pragma unroll
    for (int e=0;e<8;e++) v[e] = tile[rv+e][cr];
    *(u16x8*)&dst[(size_t)(d0+cr)*2048 + t0 + rv] = v;
  }
}

// ---------------- GEMM v4.2 (R20, unchanged): 256x256, 8-phase, reg-dbuf, 16x16x32 ----------------
template<int F32OUT>
__global__ __launch_bounds__(512, 2) void gemm8p(const u16* __restrict__ A, const u16* __restrict__ Bt,
                                                 const float* __restrict__ bias, void* __restrict__ Cv,
                                                 int M, int N, int K, int ntn)
{
  __shared__ u16 lsA[2][2][256*32];
  __shared__ u16 lsB[2][2][256*32];
  const int tid = threadIdx.x;
  const int w = tid >> 6, lane = tid & 63;
  const int wm = w >> 2, wn = w & 3;
  const int lo = lane & 15, hi = lane >> 4;

  const int nwg = gridDim.x;
  const int bid = blockIdx.x;
  const int swz = (bid & 7) * (nwg >> 3) + (bid >> 3);
  const int nt = swz % ntn, mt = swz / ntn;       // nt-fastest
  const int m0 = mt << 8, n0 = nt << 8;
  const int NT = K >> 6, NI = NT >> 1;

  const int s0 = tid, s1 = tid + 512;
  const size_t off0 = (size_t)(s0>>2)*K + (size_t)((((s0&3) ^ ((s0>>3)&3))) << 3);
  const size_t off1 = (size_t)(s1>>2)*K + (size_t)((((s1&3) ^ ((s1>>3)&3))) << 3);
  const u16* Asrc = A + (size_t)m0*K;
  const u16* Bsrc = Bt + (size_t)n0*K;

  f32x4 acc[8][4];
  f32x4 z = {0.f,0.f,0.f,0.f};
  #pragma unroll
  for (int i=0;i<8;i++)
    #pragma unroll
    for (int j=0;j<4;j++) acc[i][j] = z;

  bf16x8 aE[4], aO[4], bX[4], bY[4];

#define SLOT(T, KH, AP, BP) do { \
    const u16* as_ = Asrc + (T)*64 + (KH)*32; \
    const u16* bs_ = Bsrc + (T)*64 + (KH)*32; \
    async16(as_ + off0, &(AP)[s0*8]); \
    async16(as_ + off1, &(AP)[s1*8]); \
    async16(bs_ + off0, &(BP)[s0*8]); \
    async16(bs_ + off1, &(BP)[s1*8]); \
  } while(0)

#define RDA(SET, BUF, KS, Q) do { \
    _Pragma("unroll") \
    for (int mf=0; mf<4; ++mf){ \
      int row_ = wm*128 + (Q)*64 + mf*16 + lo; \
      SET[mf] = *(const bf16x8*)&lsA[BUF][KS][row_*32 + ((hi ^ ((row_>>1) & 3)) << 3)]; \
    } } while(0)

#define RDB(SET, BUF, KS) do { \
    _Pragma("unroll") \
    for (int nf=0; nf<4; ++nf){ \
      int row_ = wn*64 + nf*16 + lo; \
      SET[nf] = *(const bf16x8*)&lsB[BUF][KS][row_*32 + ((hi ^ ((row_>>1) & 3)) << 3)]; \
    } } while(0)

#define MM(Q, AS, BS) do { \
    __builtin_amdgcn_s_setprio(1); \
    _Pragma("unroll") \
    for (int mf=0; mf<4; ++mf) \
      _Pragma("unroll") \
      for (int nf=0; nf<4; ++nf) \
        acc[(Q)*4+mf][nf] = __builtin_amdgcn_mfma_f32_16x16x32_bf16(AS[mf], BS[nf], acc[(Q)*4+mf][nf], 0,0,0); \
    __builtin_amdgcn_s_setprio(0); \
  } while(0)

#define LGK4 do { asm volatile("s_waitcnt lgkmcnt(4)" ::: "memory"); __builtin_amdgcn_sched_barrier(0); } while(0)
#define LGK8 do { asm volatile("s_waitcnt lgkmcnt(8)" ::: "memory"); __builtin_amdgcn_sched_barrier(0); } while(0)
#define LGK0 do { asm volatile("s_waitcnt lgkmcnt(0)" ::: "memory"); __builtin_amdgcn_sched_barrier(0); } while(0)
#define VM8 asm volatile("s_waitcnt vmcnt(8)" ::: "memory")
#define VM4 asm volatile("s_waitcnt vmcnt(4)" ::: "memory")
#define VM0 asm volatile("s_waitcnt vmcnt(0)" ::: "memory")
#define BARP do { __builtin_amdgcn_s_barrier(); __builtin_amdgcn_sched_barrier(0); } while(0)
#define SBO  do { __builtin_amdgcn_sched_barrier(0); } while(0)

  SLOT(0, 0, lsA[0][0], lsB[0][0]);
  SLOT(0, 1, lsA[0][1], lsB[0][1]);
  SLOT(1, 0, lsA[1][0], lsB[1][0]);
  VM8;
  __builtin_amdgcn_s_barrier();
  __builtin_amdgcn_sched_barrier(0);
  RDA(aO, 0,0, 0); RDB(bX, 0,0);

  #pragma unroll 1
  for (int i = 0; i < NI-1; ++i){
    const int t0 = 2*i;
    RDA(aE, 0,0, 1); SLOT(t0+1,1, lsA[1][1], lsB[1][1]); LGK4; MM(0, aO, bX); VM8; BARP;   // p1
    RDA(aO, 0,1, 0); RDB(bY, 0,1);                       LGK8; MM(1, aE, bX);      SBO;    // p2
    RDA(aE, 0,1, 1); SLOT(t0+2,0, lsA[0][0], lsB[0][0]); LGK4; MM(0, aO, bY); VM8; BARP;   // p3
    RDA(aO, 1,0, 0); RDB(bX, 1,0);                       LGK8; MM(1, aE, bY);      SBO;    // p4
    RDA(aE, 1,0, 1); SLOT(t0+2,1, lsA[0][1], lsB[0][1]); LGK4; MM(0, aO, bX); VM8; BARP;   // p5
    RDA(aO, 1,1, 0); RDB(bY, 1,1);                       LGK8; MM(1, aE, bX);      SBO;    // p6
    RDA(aE, 1,1, 1); SLOT(t0+3,0, lsA[1][0], lsB[1][0]); LGK4; MM(0, aO, bY); VM8; BARP;   // p7
    RDA(aO, 0,0, 0); RDB(bX, 0,0);                       LGK8; MM(1, aE, bY);      SBO;    // p8
  }
  RDA(aE, 0,0, 1); SLOT(NT-1,1, lsA[1][1], lsB[1][1]);   LGK4; MM(0, aO, bX); VM8; BARP;   // p1
  RDA(aO, 0,1, 0); RDB(bY, 0,1);                         LGK8; MM(1, aE, bX);      SBO;    // p2
  RDA(aE, 0,1, 1);                                       LGK4; MM(0, aO, bY); VM4; BARP;   // p3
  RDA(aO, 1,0, 0); RDB(bX, 1,0);                         LGK8; MM(1, aE, bY);      SBO;    // p4
  RDA(aE, 1,0, 1);                                       LGK4; MM(0, aO, bX); VM0; BARP;   // p5
  RDA(aO, 1,1, 0); RDB(bY, 1,1);                         LGK8; MM(1, aE, bX);      SBO;    // p6
  RDA(aE, 1,1, 1);                                       LGK4; MM(0, aO, bY);      BARP;   // p7
                                                         LGK0; MM(1, aE, bY);             // p8

#undef SLOT
#undef RDA
#undef RDB
#undef MM

  float bv[4];
  #pragma unroll
  for (int nf=0;nf<4;nf++) bv[nf] = bias[n0 + wn*64 + nf*16 + lo];
  #pragma unroll
  for (int am=0;am<8;am++){
    int row = m0 + wm*128 + am*16 + hi*4;
    #pragma unroll
    for (int nf=0;nf<4;nf++){
      int col = n0 + wn*64 + nf*16 + lo;
      #pragma unroll
      for (int r=0;r<4;r++){
        float vv = acc[am][nf][r] + bv[nf];
        if (F32OUT) ((float*)Cv)[(size_t)(row+r)*N + col] = vv;
        else        ((u16*)Cv)[(size_t)(row+r)*N + col] = f2bf(vv);
      }
    }
  }
}

// ---------------- causal flash attention v5y: v5x + native bf16 cvt + guarded rescale ----------------
// grid (64 heads, 8 pairs); block 512 = 8 waves, wave owns 16 q-rows.
// Changes vs R20 (VALU cuts only): (1) P-write/epilogue use native (__bf16)
// casts (HW cvt, same RNE rounding); (2) O-rescale 32-mul loop guarded by
// wave-uniform "max grew" flag (al==1 exactly when skipped -> identity).
__global__ __launch_bounds__(512, 4) void attn_fwd(const u16* __restrict__ qkv, const u16* __restrict__ vt,
                                                   u16* __restrict__ y)
{
  __shared__ u16 kb[2][64*128];    // K tile dbuf [krow][d], bytes ^= (krow&7)<<4
  __shared__ u16 vb[2][128*64];    // V tile dbuf [d][kcol], bytes ^= (d&7)<<4
  __shared__ u16 plds[8][16*64];   // per-wave P [16 q][64 k], bytes ^= (qrow&7)<<4
  const int bh = blockIdx.x;
  const int b = bh >> 4, h = bh & 15;
  const int pair = blockIdx.y;
  const int tid = threadIdx.x;
  const int w = tid >> 6, lane = tid & 63;
  const int lo = lane & 15, hi = lane >> 4;

  const u16* Qb = qkv + (size_t)b*2048*6144 + h*128;
  const u16* Kb = Qb + 2048;
  const u16* Vb = vt + (size_t)bh*128*2048;   // [d][t]
  u16* pw = &plds[w][0];
  const float sc = 0.08838834764831845f * 1.4426950408889634f;  // 1/sqrt(128)*log2(e)
  f32x4 z = {0.f,0.f,0.f,0.f};

  #pragma unroll 1
  for (int seg = 0; seg < 2; ++seg){
    const int qt = seg ? pair : 15 - pair;
    const int qw = qt*128 + w*16;
    const int nt = qt*2 + 2;

    bf16x8 qf[4];
    #pragma unroll
    for (int kd=0;kd<4;kd++)
      qf[kd] = *(const bf16x8*)&Qb[(size_t)(qw + lo)*6144 + kd*32 + hi*8];

    f32x4 o[8];
    #pragma unroll
    for (int dj=0;dj<8;dj++) o[dj] = z;
    float mx[4], lsum[4];
    #pragma unroll
    for (int r=0;r<4;r++){ mx[r] = -3.0e38f; lsum[r] = 0.f; }

    // prologue: stage K+V tile 0 into buf 0
    #pragma unroll
    for (int i=0;i<2;i++){
      int slot = i*512 + tid;
      int kr = slot >> 4;
      int kc = ((slot & 15) << 4) ^ ((kr & 7) << 4);
      async16(Kb + (size_t)kr*6144 + (kc >> 1), &kb[0][(size_t)(i*512 + w*64)*8]);
      int vr = slot >> 3;
      int vc = ((slot & 7) << 4) ^ ((vr & 7) << 4);
      async16(Vb + (size_t)vr*2048 + (vc >> 1), &vb[0][(size_t)(i*512 + w*64)*8]);
    }
    __syncthreads();

    #pragma unroll 1
    for (int it = 0; it < nt; ++it){
      const int k0 = it*64;
      if (it + 1 < nt){
        const int kn = (it+1)*64;
        u16* kdst = kb[(it+1)&1];
        u16* vdst = vb[(it+1)&1];
        #pragma unroll
        for (int i=0;i<2;i++){
          int slot = i*512 + tid;
          int kr = slot >> 4;
          int kc = ((slot & 15) << 4) ^ ((kr & 7) << 4);
          async16(Kb + (size_t)(kn + kr)*6144 + (kc >> 1), &kdst[(size_t)(i*512 + w*64)*8]);
          int vr = slot >> 3;
          int vc = ((slot & 7) << 4) ^ ((vr & 7) << 4);
          async16(Vb + (size_t)vr*2048 + kn + (vc >> 1), &vdst[(size_t)(i*512 + w*64)*8]);
        }
      }
      if (k0 <= qw + 15){
        const u16* kcur = kb[it&1];
        const u16* vcur = vb[it&1];
        // ---- QK^T ----
        f32x4 s[4];
        #pragma unroll
        for (int t=0;t<4;t++) s[t] = z;
        __builtin_amdgcn_s_setprio(1);
        #pragma unroll
        for (int t=0;t<4;t++){
          #pragma unroll
          for (int kd=0;kd<4;kd++){
            int row = t*16 + lo;
            int cb = (kd*64 + hi*16) ^ ((lo & 7) << 4);
            bf16x8 kk = *(const bf16x8*)&kcur[row*128 + (cb >> 1)];
            s[t] = __builtin_amdgcn_mfma_f32_16x16x32_bf16(qf[kd], kk, s[t], 0,0,0);
          }
        }
        __builtin_amdgcn_s_setprio(0);

        // ---- causal mask + online softmax ----
        if (k0 + 63 > qw) {
          #pragma unroll
          for (int t=0;t<4;t++)
            #pragma unroll
            for (int r=0;r<4;r++){
              int q = qw + hi*4 + r;
              int k = k0 + t*16 + lo;
              if (k > q) s[t][r] = -3.0e38f;
            }
        }
        float tm[4], al[4];
        int grow = 0;
        #pragma unroll
        for (int r=0;r<4;r++){
          float t0 = fmaxf(fmaxf(s[0][r], s[1][r]), fmaxf(s[2][r], s[3][r]));
          t0 = fmaxf(t0, __shfl_xor(t0, 1));
          t0 = fmaxf(t0, __shfl_xor(t0, 2));
          t0 = fmaxf(t0, __shfl_xor(t0, 4));
          t0 = fmaxf(t0, __shfl_xor(t0, 8));
          tm[r] = t0 * sc;
          grow |= (tm[r] > mx[r]) ? 1 : 0;
        }
        #pragma unroll
        for (int r=0;r<4;r++){
          float mn = fmaxf(mx[r], tm[r]);
          al[r] = exp2f(mx[r] - mn);
          mx[r] = mn;
          float p0 = exp2f(fmaf(s[0][r], sc, -mn));
          float p1 = exp2f(fmaf(s[1][r], sc, -mn));
          float p2 = exp2f(fmaf(s[2][r], sc, -mn));
          float p3 = exp2f(fmaf(s[3][r], sc, -mn));
          float sum = (p0 + p1) + (p2 + p3);
          sum += __shfl_xor(sum, 1);
          sum += __shfl_xor(sum, 2);
          sum += __shfl_xor(sum, 4);
          sum += __shfl_xor(sum, 8);
          lsum[r] = lsum[r]*al[r] + sum;
          int row = hi*4 + r;
          int sw = (row & 7) << 4;
          u16* prow = pw + row*64;
          prow[((     lo*2) ^ sw) >> 1] = f2bfn(p0);
          prow[((32 + lo*2) ^ sw) >> 1] = f2bfn(p1);
          prow[((64 + lo*2) ^ sw) >> 1] = f2bfn(p2);
          prow[((96 + lo*2) ^ sw) >> 1] = f2bfn(p3);
        }
        // O-rescale only when some row's max grew (else al==1 exactly)
        if (__any(grow)) {
          #pragma unroll
          for (int dj=0;dj<8;dj++)
            #pragma unroll
            for (int r=0;r<4;r++) o[dj][r] *= al[r];
        }

        // ---- PV: O += P[16x64] * V[64x128], V from LDS (swizzled) ----
        bf16x8 pa[2];
        #pragma unroll
        for (int kf=0;kf<2;kf++)
          pa[kf] = *(const bf16x8*)&pw[(lo*128 + ((kf*64 + hi*16) ^ ((lo & 7) << 4))) >> 1];
        __builtin_amdgcn_s_setprio(1);
        #pragma unroll
        for (int dj=0;dj<8;dj++){
          int row = dj*16 + lo;
          int cb0 = (hi*16)      ^ ((lo & 7) << 4);
          int cb1 = (64 + hi*16) ^ ((lo & 7) << 4);
          bf16x8 vv0 = *(const bf16x8*)&vcur[row*64 + (cb0 >> 1)];
          bf16x8 vv1 = *(const bf16x8*)&vcur[row*64 + (cb1 >> 1)];
          o[dj] = __builtin_amdgcn_mfma_f32_16x16x32_bf16(pa[0], vv0, o[dj], 0,0,0);
          o[dj] = __builtin_amdgcn_mfma_f32_16x16x32_bf16(pa[1], vv1, o[dj], 0,0,0);
        }
        __builtin_amdgcn_s_setprio(0);
      }
      __syncthreads();   // drains stage loads (vmcnt) + releases buffers
    }

    // ---- epilogue ----
    #pragma unroll
    for (int r=0;r<4;r++){
      float inv = 1.0f / lsum[r];
      size_t row = (size_t)(b*2048 + qw + hi*4 + r);
      #pragma unroll
      for (int dj=0;dj<8;dj++)
        y[row*2048 + h*128 + dj*16 + lo] = f2bfn(o[dj][r] * inv);
    }
    __syncthreads();   // keep segments separated (kb/vb reuse)
  }
}

extern "C" void kernel_launch(void* const* d_in, const int* in_sizes, int n_in,
                              void* d_out, int out_size, void* d_ws, size_t ws_size,
                              hipStream_t stream) {
  (void)in_sizes; (void)n_in; (void)out_size; (void)ws_size;
  const float* x      = (const float*)d_in[0];  // [8192][2048] f32
  const float* w_attn = (const float*)d_in[1];  // [2048][6144] f32
  const float* b_attn = (const float*)d_in[2];  // [6144] f32
  const float* w_proj = (const float*)d_in[3];  // [2048][2048] f32
  const float* b_proj = (const float*)d_in[4];  // [2048] f32
  float* out = (float*)d_out;                   // [8192][2048] f32

  char* ws = (char*)d_ws;
  u16* xbf = (u16*)(ws);                     // [8192][2048] bf16, 32 MB; reused as y
  u16* wT  = (u16*)(ws + 33554432);          // [6144][2048] bf16, 24 MB
  u16* pT  = (u16*)(ws + 58720256);          // [2048][2048] bf16,  8 MB
  u16* qkv = (u16*)(ws + 67108864);          // [8192][6144] bf16, 96 MB
  u16* vt  = (u16*)(ws + 167772160);         // [64][128][2048] bf16, 32 MB
  u16* y   = xbf;

  cvt_f2b<<<16384, 256, 0, stream>>>(x, xbf, 8192*2048);
  transpose2d_f2b<<<dim3(96,32), 256, 0, stream>>>(w_attn, wT, 2048, 6144);
  transpose2d_f2b<<<dim3(32,32), 256, 0, stream>>>(w_proj, pT, 2048, 2048);
  // QKV: 32 m-tiles x 24 n-tiles = 768 blocks (nt-fastest XCD chunks)
  gemm8p<0><<<768, 512, 0, stream>>>(xbf, wT, b_attn, qkv, 8192, 6144, 2048, 24);
  transpose_v<<<dim3(2,32,64), 256, 0, stream>>>(qkv, vt);
  // attn: grid (64 heads, 8 pairs) -> all pairs of a head on one XCD
  attn_fwd<<<dim3(64,8), 512, 0, stream>>>(qkv, vt, y);
  // proj: 32 m-tiles x 8 n-tiles = 256 blocks
  gemm8p<1><<<256, 512, 0, stream>>>(y, pT, b_proj, out, 8192, 2048, 2048, 8);
}

// Round 22
// 477.768 us; speedup vs baseline: 1.0066x; 1.0066x over previous
//
#include <hip/hip_runtime.h>
#include <hip/hip_bf16.h>
#include <stdint.h>

typedef unsigned short u16;
typedef __bf16 bf16x8 __attribute__((ext_vector_type(8)));
typedef unsigned short u16x8 __attribute__((ext_vector_type(8)));
typedef float f32x4 __attribute__((ext_vector_type(4)));

__device__ __forceinline__ float bf2f(u16 u){ union{float f; unsigned i;} v; v.i = ((unsigned)u)<<16; return v.f; }
__device__ __forceinline__ u16 f2bf(float f){ union{float f; unsigned i;} v; v.f=f; unsigned r = v.i + 0x7FFFu + ((v.i>>16)&1u); return (u16)(r>>16); }

__device__ __forceinline__ void async16(const void* g, void* l){
  __builtin_amdgcn_global_load_lds((const __attribute__((address_space(1))) void*)g,
                                   (__attribute__((address_space(3))) void*)l, 16, 0, 0);
}

// ---------------- f32 -> bf16 elementwise cast ----------------
__global__ __launch_bounds__(256) void cvt_f2b(const float* __restrict__ src, u16* __restrict__ dst, int n)
{
  int i = (blockIdx.x * 256 + threadIdx.x) * 4;
  if (i < n) {
    float4 v = *(const float4*)&src[i];
    ushort4 o;
    o.x = f2bf(v.x); o.y = f2bf(v.y); o.z = f2bf(v.z); o.w = f2bf(v.w);
    *(ushort4*)&dst[i] = o;
  }
}

// ---------------- f32 src -> bf16 transposed dst, 64x64 tiles ----------------
__global__ __launch_bounds__(256) void transpose2d_f2b(const float* __restrict__ src, u16* __restrict__ dst,
                                                       int src_rows, int src_cols)
{
  __shared__ u16 tile[64][72];
  const int r0 = blockIdx.y << 6, c0 = blockIdx.x << 6;
  const int t = threadIdx.x;
  #pragma unroll
  for (int i=0;i<4;i++){
    int slot = t + (i<<8);
    int r = slot >> 4, cv = (slot & 15) << 2;
    float4 v = *(const float4*)&src[(size_t)(r0+r)*src_cols + c0 + cv];
    tile[r][cv+0] = f2bf(v.x); tile[r][cv+1] = f2bf(v.y);
    tile[r][cv+2] = f2bf(v.z); tile[r][cv+3] = f2bf(v.w);
  }
  __syncthreads();
  #pragma unroll
  for (int i=0;i<2;i++){
    int slot = t + (i<<8);
    int cr = slot >> 3, rv = (slot & 7) << 3;
    u16x8 v;
    #pragma unroll
    for (int e=0;e<8;e++) v[e] = tile[rv+e][cr];
    *(u16x8*)&dst[(size_t)(c0+cr)*src_rows + r0 + rv] = v;
  }
}

// ---------------- V transpose ----------------
__global__ __launch_bounds__(256) void transpose_v(const u16* __restrict__ qkv, u16* __restrict__ vt)
{
  __shared__ u16 tile[64][72];
  const int bh = blockIdx.z;
  const int b = bh >> 4, h = bh & 15;
  const u16* src = qkv + (size_t)b*2048*6144 + 4096 + h*128;
  u16* dst = vt + (size_t)bh*128*2048;
  const int t0 = blockIdx.y << 6, d0 = blockIdx.x << 6;
  const int t = threadIdx.x;
  #pragma unroll
  for (int i=0;i<2;i++){
    int slot = t + (i<<8);
    int r = slot >> 3, cv = (slot & 7) << 3;
    *(u16x8*)&tile[r][cv] = *(const u16x8*)&src[(size_t)(t0+r)*6144 + d0 + cv];
  }
  __syncthreads();
  #pragma unroll
  for (int i=0;i<2;i++){
    int slot = t + (i<<8);
    int cr = slot >> 3, rv = (slot & 7) << 3;
    u16x8 v;
    #pragma unroll
    for (int e=0;e<8;e++) v[e] = tile[rv+e][cr];
    *(u16x8*)&dst[(size_t)(d0+cr)*2048 + t0 + rv] = v;
  }
}

// ---------------- GEMM v4.2 (R20 best): 256x256, 8-phase, reg-dbuf, 16x16x32 ----------------
// 0 bank conflicts (16-row reads + (row>>1)&3 parity), nt-fastest XCD chunks,
// odd-phase-only barriers (hazard-proven), counted vmcnt(8), setprio MFMA.
template<int F32OUT>
__global__ __launch_bounds__(512, 2) void gemm8p(const u16* __restrict__ A, const u16* __restrict__ Bt,
                                                 const float* __restrict__ bias, void* __restrict__ Cv,
                                                 int M, int N, int K, int ntn)
{
  __shared__ u16 lsA[2][2][256*32];
  __shared__ u16 lsB[2][2][256*32];
  const int tid = threadIdx.x;
  const int w = tid >> 6, lane = tid & 63;
  const int wm = w >> 2, wn = w & 3;
  const int lo = lane & 15, hi = lane >> 4;

  const int nwg = gridDim.x;
  const int bid = blockIdx.x;
  const int swz = (bid & 7) * (nwg >> 3) + (bid >> 3);
  const int nt = swz % ntn, mt = swz / ntn;       // nt-fastest
  const int m0 = mt << 8, n0 = nt << 8;
  const int NT = K >> 6, NI = NT >> 1;

  const int s0 = tid, s1 = tid + 512;
  const size_t off0 = (size_t)(s0>>2)*K + (size_t)((((s0&3) ^ ((s0>>3)&3))) << 3);
  const size_t off1 = (size_t)(s1>>2)*K + (size_t)((((s1&3) ^ ((s1>>3)&3))) << 3);
  const u16* Asrc = A + (size_t)m0*K;
  const u16* Bsrc = Bt + (size_t)n0*K;

  f32x4 acc[8][4];
  f32x4 z = {0.f,0.f,0.f,0.f};
  #pragma unroll
  for (int i=0;i<8;i++)
    #pragma unroll
    for (int j=0;j<4;j++) acc[i][j] = z;

  bf16x8 aE[4], aO[4], bX[4], bY[4];

#define SLOT(T, KH, AP, BP) do { \
    const u16* as_ = Asrc + (T)*64 + (KH)*32; \
    const u16* bs_ = Bsrc + (T)*64 + (KH)*32; \
    async16(as_ + off0, &(AP)[s0*8]); \
    async16(as_ + off1, &(AP)[s1*8]); \
    async16(bs_ + off0, &(BP)[s0*8]); \
    async16(bs_ + off1, &(BP)[s1*8]); \
  } while(0)

#define RDA(SET, BUF, KS, Q) do { \
    _Pragma("unroll") \
    for (int mf=0; mf<4; ++mf){ \
      int row_ = wm*128 + (Q)*64 + mf*16 + lo; \
      SET[mf] = *(const bf16x8*)&lsA[BUF][KS][row_*32 + ((hi ^ ((row_>>1) & 3)) << 3)]; \
    } } while(0)

#define RDB(SET, BUF, KS) do { \
    _Pragma("unroll") \
    for (int nf=0; nf<4; ++nf){ \
      int row_ = wn*64 + nf*16 + lo; \
      SET[nf] = *(const bf16x8*)&lsB[BUF][KS][row_*32 + ((hi ^ ((row_>>1) & 3)) << 3)]; \
    } } while(0)

#define MM(Q, AS, BS) do { \
    __builtin_amdgcn_s_setprio(1); \
    _Pragma("unroll") \
    for (int mf=0; mf<4; ++mf) \
      _Pragma("unroll") \
      for (int nf=0; nf<4; ++nf) \
        acc[(Q)*4+mf][nf] = __builtin_amdgcn_mfma_f32_16x16x32_bf16(AS[mf], BS[nf], acc[(Q)*4+mf][nf], 0,0,0); \
    __builtin_amdgcn_s_setprio(0); \
  } while(0)

#define LGK4 do { asm volatile("s_waitcnt lgkmcnt(4)" ::: "memory"); __builtin_amdgcn_sched_barrier(0); } while(0)
#define LGK8 do { asm volatile("s_waitcnt lgkmcnt(8)" ::: "memory"); __builtin_amdgcn_sched_barrier(0); } while(0)
#define LGK0 do { asm volatile("s_waitcnt lgkmcnt(0)" ::: "memory"); __builtin_amdgcn_sched_barrier(0); } while(0)
#define VM8 asm volatile("s_waitcnt vmcnt(8)" ::: "memory")
#define VM4 asm volatile("s_waitcnt vmcnt(4)" ::: "memory")
#define VM0 asm volatile("s_waitcnt vmcnt(0)" ::: "memory")
#define BARP do { __builtin_amdgcn_s_barrier(); __builtin_amdgcn_sched_barrier(0); } while(0)
#define SBO  do { __builtin_amdgcn_sched_barrier(0); } while(0)

  SLOT(0, 0, lsA[0][0], lsB[0][0]);
  SLOT(0, 1, lsA[0][1], lsB[0][1]);
  SLOT(1, 0, lsA[1][0], lsB[1][0]);
  VM8;
  __builtin_amdgcn_s_barrier();
  __builtin_amdgcn_sched_barrier(0);
  RDA(aO, 0,0, 0); RDB(bX, 0,0);

  #pragma unroll 1
  for (int i = 0; i < NI-1; ++i){
    const int t0 = 2*i;
    RDA(aE, 0,0, 1); SLOT(t0+1,1, lsA[1][1], lsB[1][1]); LGK4; MM(0, aO, bX); VM8; BARP;   // p1
    RDA(aO, 0,1, 0); RDB(bY, 0,1);                       LGK8; MM(1, aE, bX);      SBO;    // p2
    RDA(aE, 0,1, 1); SLOT(t0+2,0, lsA[0][0], lsB[0][0]); LGK4; MM(0, aO, bY); VM8; BARP;   // p3
    RDA(aO, 1,0, 0); RDB(bX, 1,0);                       LGK8; MM(1, aE, bY);      SBO;    // p4
    RDA(aE, 1,0, 1); SLOT(t0+2,1, lsA[0][1], lsB[0][1]); LGK4; MM(0, aO, bX); VM8; BARP;   // p5
    RDA(aO, 1,1, 0); RDB(bY, 1,1);                       LGK8; MM(1, aE, bX);      SBO;    // p6
    RDA(aE, 1,1, 1); SLOT(t0+3,0, lsA[1][0], lsB[1][0]); LGK4; MM(0, aO, bY); VM8; BARP;   // p7
    RDA(aO, 0,0, 0); RDB(bX, 0,0);                       LGK8; MM(1, aE, bY);      SBO;    // p8
  }
  RDA(aE, 0,0, 1); SLOT(NT-1,1, lsA[1][1], lsB[1][1]);   LGK4; MM(0, aO, bX); VM8; BARP;   // p1
  RDA(aO, 0,1, 0); RDB(bY, 0,1);                         LGK8; MM(1, aE, bX);      SBO;    // p2
  RDA(aE, 0,1, 1);                                       LGK4; MM(0, aO, bY); VM4; BARP;   // p3
  RDA(aO, 1,0, 0); RDB(bX, 1,0);                         LGK8; MM(1, aE, bY);      SBO;    // p4
  RDA(aE, 1,0, 1);                                       LGK4; MM(0, aO, bX); VM0; BARP;   // p5
  RDA(aO, 1,1, 0); RDB(bY, 1,1);                         LGK8; MM(1, aE, bX);      SBO;    // p6
  RDA(aE, 1,1, 1);                                       LGK4; MM(0, aO, bY);      BARP;   // p7
                                                         LGK0; MM(1, aE, bY);             // p8

#undef SLOT
#undef RDA
#undef RDB
#undef MM

  float bv[4];
  #pragma unroll
  for (int nf=0;nf<4;nf++) bv[nf] = bias[n0 + wn*64 + nf*16 + lo];
  #pragma unroll
  for (int am=0;am<8;am++){
    int row = m0 + wm*128 + am*16 + hi*4;
    #pragma unroll
    for (int nf=0;nf<4;nf++){
      int col = n0 + wn*64 + nf*16 + lo;
      #pragma unroll
      for (int r=0;r<4;r++){
        float vv = acc[am][nf][r] + bv[nf];
        if (F32OUT) ((float*)Cv)[(size_t)(row+r)*N + col] = vv;
        else        ((u16*)Cv)[(size_t)(row+r)*N + col] = f2bf(vv);
      }
    }
  }
}

// ---------------- causal flash attention v5x (R20 best) ----------------
// grid (64 heads, 8 pairs); block 512 = 8 waves, wave owns 16 q-rows.
// Triangle pairing; K+V gload_lds dbuf (XOR-swizzled, 80 KB -> 2 blk/CU);
// per-wave P LDS swizzled; single-path online softmax; head->XCD affinity.
__global__ __launch_bounds__(512, 4) void attn_fwd(const u16* __restrict__ qkv, const u16* __restrict__ vt,
                                                   u16* __restrict__ y)
{
  __shared__ u16 kb[2][64*128];    // K tile dbuf [krow][d], bytes ^= (krow&7)<<4
  __shared__ u16 vb[2][128*64];    // V tile dbuf [d][kcol], bytes ^= (d&7)<<4
  __shared__ u16 plds[8][16*64];   // per-wave P [16 q][64 k], bytes ^= (qrow&7)<<4
  const int bh = blockIdx.x;
  const int b = bh >> 4, h = bh & 15;
  const int pair = blockIdx.y;
  const int tid = threadIdx.x;
  const int w = tid >> 6, lane = tid & 63;
  const int lo = lane & 15, hi = lane >> 4;

  const u16* Qb = qkv + (size_t)b*2048*6144 + h*128;
  const u16* Kb = Qb + 2048;
  const u16* Vb = vt + (size_t)bh*128*2048;   // [d][t]
  u16* pw = &plds[w][0];
  const float sc = 0.08838834764831845f * 1.4426950408889634f;  // 1/sqrt(128)*log2(e)
  f32x4 z = {0.f,0.f,0.f,0.f};

  #pragma unroll 1
  for (int seg = 0; seg < 2; ++seg){
    const int qt = seg ? pair : 15 - pair;
    const int qw = qt*128 + w*16;
    const int nt = qt*2 + 2;

    bf16x8 qf[4];
    #pragma unroll
    for (int kd=0;kd<4;kd++)
      qf[kd] = *(const bf16x8*)&Qb[(size_t)(qw + lo)*6144 + kd*32 + hi*8];

    f32x4 o[8];
    #pragma unroll
    for (int dj=0;dj<8;dj++) o[dj] = z;
    float mx[4], lsum[4];
    #pragma unroll
    for (int r=0;r<4;r++){ mx[r] = -3.0e38f; lsum[r] = 0.f; }

    // prologue: stage K+V tile 0 into buf 0
    #pragma unroll
    for (int i=0;i<2;i++){
      int slot = i*512 + tid;
      int kr = slot >> 4;
      int kc = ((slot & 15) << 4) ^ ((kr & 7) << 4);
      async16(Kb + (size_t)kr*6144 + (kc >> 1), &kb[0][(size_t)(i*512 + w*64)*8]);
      int vr = slot >> 3;
      int vc = ((slot & 7) << 4) ^ ((vr & 7) << 4);
      async16(Vb + (size_t)vr*2048 + (vc >> 1), &vb[0][(size_t)(i*512 + w*64)*8]);
    }
    __syncthreads();

    #pragma unroll 1
    for (int it = 0; it < nt; ++it){
      const int k0 = it*64;
      if (it + 1 < nt){
        const int kn = (it+1)*64;
        u16* kdst = kb[(it+1)&1];
        u16* vdst = vb[(it+1)&1];
        #pragma unroll
        for (int i=0;i<2;i++){
          int slot = i*512 + tid;
          int kr = slot >> 4;
          int kc = ((slot & 15) << 4) ^ ((kr & 7) << 4);
          async16(Kb + (size_t)(kn + kr)*6144 + (kc >> 1), &kdst[(size_t)(i*512 + w*64)*8]);
          int vr = slot >> 3;
          int vc = ((slot & 7) << 4) ^ ((vr & 7) << 4);
          async16(Vb + (size_t)vr*2048 + kn + (vc >> 1), &vdst[(size_t)(i*512 + w*64)*8]);
        }
      }
      if (k0 <= qw + 15){
        const u16* kcur = kb[it&1];
        const u16* vcur = vb[it&1];
        // ---- QK^T ----
        f32x4 s[4];
        #pragma unroll
        for (int t=0;t<4;t++) s[t] = z;
        __builtin_amdgcn_s_setprio(1);
        #pragma unroll
        for (int t=0;t<4;t++){
          #pragma unroll
          for (int kd=0;kd<4;kd++){
            int row = t*16 + lo;
            int cb = (kd*64 + hi*16) ^ ((lo & 7) << 4);
            bf16x8 kk = *(const bf16x8*)&kcur[row*128 + (cb >> 1)];
            s[t] = __builtin_amdgcn_mfma_f32_16x16x32_bf16(qf[kd], kk, s[t], 0,0,0);
          }
        }
        __builtin_amdgcn_s_setprio(0);

        // ---- causal mask + online softmax (single path) ----
        if (k0 + 63 > qw) {
          #pragma unroll
          for (int t=0;t<4;t++)
            #pragma unroll
            for (int r=0;r<4;r++){
              int q = qw + hi*4 + r;
              int k = k0 + t*16 + lo;
              if (k > q) s[t][r] = -3.0e38f;
            }
        }
        #pragma unroll
        for (int r=0;r<4;r++){
          float tm = fmaxf(fmaxf(s[0][r], s[1][r]), fmaxf(s[2][r], s[3][r]));
          tm = fmaxf(tm, __shfl_xor(tm, 1));
          tm = fmaxf(tm, __shfl_xor(tm, 2));
          tm = fmaxf(tm, __shfl_xor(tm, 4));
          tm = fmaxf(tm, __shfl_xor(tm, 8));
          tm *= sc;
          float mn = fmaxf(mx[r], tm);
          float al = exp2f(mx[r] - mn);
          mx[r] = mn;
          float p0 = exp2f(fmaf(s[0][r], sc, -mn));
          float p1 = exp2f(fmaf(s[1][r], sc, -mn));
          float p2 = exp2f(fmaf(s[2][r], sc, -mn));
          float p3 = exp2f(fmaf(s[3][r], sc, -mn));
          float sum = (p0 + p1) + (p2 + p3);
          sum += __shfl_xor(sum, 1);
          sum += __shfl_xor(sum, 2);
          sum += __shfl_xor(sum, 4);
          sum += __shfl_xor(sum, 8);
          lsum[r] = lsum[r]*al + sum;
          #pragma unroll
          for (int dj=0;dj<8;dj++) o[dj][r] *= al;
          int row = hi*4 + r;
          int sw = (row & 7) << 4;
          u16* prow = pw + row*64;
          prow[((     lo*2) ^ sw) >> 1] = f2bf(p0);
          prow[((32 + lo*2) ^ sw) >> 1] = f2bf(p1);
          prow[((64 + lo*2) ^ sw) >> 1] = f2bf(p2);
          prow[((96 + lo*2) ^ sw) >> 1] = f2bf(p3);
        }

        // ---- PV: O += P[16x64] * V[64x128], V from LDS (swizzled) ----
        bf16x8 pa[2];
        #pragma unroll
        for (int kf=0;kf<2;kf++)
          pa[kf] = *(const bf16x8*)&pw[(lo*128 + ((kf*64 + hi*16) ^ ((lo & 7) << 4))) >> 1];
        __builtin_amdgcn_s_setprio(1);
        #pragma unroll
        for (int dj=0;dj<8;dj++){
          int row = dj*16 + lo;
          int cb0 = (hi*16)      ^ ((lo & 7) << 4);
          int cb1 = (64 + hi*16) ^ ((lo & 7) << 4);
          bf16x8 vv0 = *(const bf16x8*)&vcur[row*64 + (cb0 >> 1)];
          bf16x8 vv1 = *(const bf16x8*)&vcur[row*64 + (cb1 >> 1)];
          o[dj] = __builtin_amdgcn_mfma_f32_16x16x32_bf16(pa[0], vv0, o[dj], 0,0,0);
          o[dj] = __builtin_amdgcn_mfma_f32_16x16x32_bf16(pa[1], vv1, o[dj], 0,0,0);
        }
        __builtin_amdgcn_s_setprio(0);
      }
      __syncthreads();   // drains stage loads (vmcnt) + releases buffers
    }

    // ---- epilogue ----
    #pragma unroll
    for (int r=0;r<4;r++){
      float inv = 1.0f / lsum[r];
      size_t row = (size_t)(b*2048 + qw + hi*4 + r);
      #pragma unroll
      for (int dj=0;dj<8;dj++)
        y[row*2048 + h*128 + dj*16 + lo] = f2bf(o[dj][r] * inv);
    }
    __syncthreads();   // keep segments separated (kb/vb reuse)
  }
}

extern "C" void kernel_launch(void* const* d_in, const int* in_sizes, int n_in,
                              void* d_out, int out_size, void* d_ws, size_t ws_size,
                              hipStream_t stream) {
  (void)in_sizes; (void)n_in; (void)out_size; (void)ws_size;
  const float* x      = (const float*)d_in[0];  // [8192][2048] f32
  const float* w_attn = (const float*)d_in[1];  // [2048][6144] f32
  const float* b_attn = (const float*)d_in[2];  // [6144] f32
  const float* w_proj = (const float*)d_in[3];  // [2048][2048] f32
  const float* b_proj = (const float*)d_in[4];  // [2048] f32
  float* out = (float*)d_out;                   // [8192][2048] f32

  char* ws = (char*)d_ws;
  u16* xbf = (u16*)(ws);                     // [8192][2048] bf16, 32 MB; reused as y
  u16* wT  = (u16*)(ws + 33554432);          // [6144][2048] bf16, 24 MB
  u16* pT  = (u16*)(ws + 58720256);          // [2048][2048] bf16,  8 MB
  u16* qkv = (u16*)(ws + 67108864);          // [8192][6144] bf16, 96 MB
  u16* vt  = (u16*)(ws + 167772160);         // [64][128][2048] bf16, 32 MB
  u16* y   = xbf;

  cvt_f2b<<<16384, 256, 0, stream>>>(x, xbf, 8192*2048);
  transpose2d_f2b<<<dim3(96,32), 256, 0, stream>>>(w_attn, wT, 2048, 6144);
  transpose2d_f2b<<<dim3(32,32), 256, 0, stream>>>(w_proj, pT, 2048, 2048);
  // QKV: 32 m-tiles x 24 n-tiles = 768 blocks (nt-fastest XCD chunks)
  gemm8p<0><<<768, 512, 0, stream>>>(xbf, wT, b_attn, qkv, 8192, 6144, 2048, 24);
  transpose_v<<<dim3(2,32,64), 256, 0, stream>>>(qkv, vt);
  // attn: grid (64 heads, 8 pairs) -> all pairs of a head on one XCD
  attn_fwd<<<dim3(64,8), 512, 0, stream>>>(qkv, vt, y);
  // proj: 32 m-tiles x 8 n-tiles = 256 blocks
  gemm8p<1><<<256, 512, 0, stream>>>(y, pT, b_proj, out, 8192, 2048, 2048, 8);
}